// Round 2
// baseline (714.995 us; speedup 1.0000x reference)
//
#include <hip/hip_runtime.h>
#include <math.h>

// B=128, N=4096, Din=128, D=128, S(slots)=8, H=256, 3 iterations.
// MFMA 16x16x32 bf16 layouts (verified m89/m120):
//   C/D: col = lane&15, row = (lane>>4)*4 + reg
//   A  : A[m = lane&15][k = (lane>>4)*8 + j], j in [0,8)
//   B  : B[k = (lane>>4)*8 + j][n = lane&15]
// k is stored A-frag-swizzled per 64-row tile: flat = ((a_mt*4+ks)*64 + lane)*8 + j
// so k_attn A-loads are 1KB-coalesced per instruction.

typedef __attribute__((ext_vector_type(4))) float fx4;
typedef __attribute__((ext_vector_type(8))) short sx8;
typedef __attribute__((ext_vector_type(8))) __bf16 bfx8;
typedef __attribute__((ext_vector_type(4))) unsigned short ux4;

static __device__ __forceinline__ fx4 MFMA(sx8 a, sx8 b, fx4 c) {
  return __builtin_amdgcn_mfma_f32_16x16x32_bf16(
      __builtin_bit_cast(bfx8, a), __builtin_bit_cast(bfx8, b), c, 0, 0, 0);
}

static __device__ __forceinline__ unsigned short f2bf(float f) {
  union { float f; unsigned u; } x; x.f = f;
  unsigned r = x.u + 0x7fffu + ((x.u >> 16) & 1u);  // RNE
  return (unsigned short)(r >> 16);
}
static __device__ __forceinline__ float bf2f(unsigned short u) {
  union { unsigned u; float f; } x; x.u = ((unsigned)u) << 16; return x.f;
}

// ---------------- prep: slots init + bf16 weight packing ----------------
__global__ __launch_bounds__(256) void k_prep(
    const float* __restrict__ noise, const float* __restrict__ mu,
    const float* __restrict__ lsig, const float* __restrict__ Wq,
    const float* __restrict__ Wk, const float* __restrict__ Wv,
    const float* __restrict__ Wih, const float* __restrict__ Whh,
    const float* __restrict__ W1, const float* __restrict__ W2,
    float* __restrict__ slots, unsigned short* __restrict__ wswz,
    unsigned short* __restrict__ wq_b, unsigned short* __restrict__ wih_b,
    unsigned short* __restrict__ whh_b, unsigned short* __restrict__ w1_b,
    unsigned short* __restrict__ w2_b) {
  int idx = blockIdx.x * 256 + threadIdx.x;
  if (idx < 131072) {
    int d = idx & 127;
    slots[idx] = mu[d] + expf(lsig[d]) * noise[idx];
    return;
  }
  idx -= 131072;
  if (idx < 32768) {  // Wkv swizzled into B-frag blocks: [(nt*4+ks)*64+lane]*8+j
    int j = idx & 7, bo = idx >> 3;
    int lane = bo & 63, ntks = bo >> 6;
    int ks = ntks & 3, nt = ntks >> 2;
    int n = nt * 16 + (lane & 15);
    int kk = ks * 32 + (lane >> 4) * 8 + j;
    float wv = (n < 128) ? Wk[n * 128 + kk] : Wv[(n - 128) * 128 + kk];
    wswz[idx] = f2bf(wv);
    return;
  }
  idx -= 32768;
  if (idx < 16384) { wq_b[idx] = f2bf(Wq[idx] * 0.08838834764831845f); return; }
  idx -= 16384;
  if (idx < 49152) { wih_b[idx] = f2bf(Wih[idx]); return; }
  idx -= 49152;
  if (idx < 49152) { whh_b[idx] = f2bf(Whh[idx]); return; }
  idx -= 49152;
  if (idx < 32768) { w1_b[idx] = f2bf(W1[idx]); return; }
  idx -= 32768;
  w2_b[idx] = f2bf(W2[idx]);
}

// ---------------- fused LN(x) + [k|v] GEMM, LDS-staged coalesced stores ----------------
// block = 256 thr (4 waves), 64 rows/block (= one attn tile).
// wave w: mstrip=w>>1 (32 rows), nstrip=w&1 (0 -> k cols, 1 -> v cols)
__global__ __launch_bounds__(256) void k_lnkv(
    const float* __restrict__ x, const unsigned short* __restrict__ wswz,
    unsigned short* __restrict__ kswz, unsigned short* __restrict__ vb) {
  __shared__ __align__(16) char smem[32768];
  short* xf = (short*)smem;                             // [0,16384) LN'd A-frags
  unsigned short* kst = (unsigned short*)smem;          // overlay [0,16384)
  unsigned short* vst = (unsigned short*)(smem + 16384);// [16384,32768)
  int tid = threadIdx.x;
  int w = tid >> 6, l = tid & 63;
  int r = l & 15, seg = l >> 4;
  long rowbase = (long)blockIdx.x * 64;
  {
    const float* xp = x + (rowbase + w * 16 + r) * 128 + seg * 32;
    float v[32];
    float s = 0.f, s2 = 0.f;
#pragma unroll
    for (int i = 0; i < 8; i++) {
      fx4 t = *(const fx4*)(xp + i * 4);
      v[i * 4 + 0] = t.x; v[i * 4 + 1] = t.y; v[i * 4 + 2] = t.z; v[i * 4 + 3] = t.w;
      s += t.x + t.y + t.z + t.w;
      s2 += t.x * t.x + t.y * t.y + t.z * t.z + t.w * t.w;
    }
    s += __shfl_xor(s, 16, 64);  s += __shfl_xor(s, 32, 64);
    s2 += __shfl_xor(s2, 16, 64); s2 += __shfl_xor(s2, 32, 64);
    float mean = s * 0.0078125f;
    float var = s2 * 0.0078125f - mean * mean;
    float rstd = rsqrtf(var + 1e-5f);
#pragma unroll
    for (int q = 0; q < 4; q++) {
      sx8 t;
#pragma unroll
      for (int j = 0; j < 8; j++) t[j] = (short)f2bf((v[q * 8 + j] - mean) * rstd);
      *(sx8*)&xf[((w * 4 + seg) * 64 + (r + 16 * q)) * 8] = t;
    }
  }
  __syncthreads();
  int mstrip = w >> 1, nstrip = w & 1;
  const fx4 z4 = {0.f, 0.f, 0.f, 0.f};
  fx4 acc[2][8];
#pragma unroll
  for (int a = 0; a < 2; a++)
#pragma unroll
    for (int b = 0; b < 8; b++) acc[a][b] = z4;
#pragma unroll
  for (int ks = 0; ks < 4; ks++) {
    sx8 a0 = *(const sx8*)&xf[(((mstrip * 2 + 0) * 4 + ks) * 64 + l) * 8];
    sx8 a1 = *(const sx8*)&xf[(((mstrip * 2 + 1) * 4 + ks) * 64 + l) * 8];
#pragma unroll
    for (int nt = 0; nt < 8; nt++) {
      sx8 bfr = *(const sx8*)(wswz + (((nstrip * 8 + nt) * 4 + ks) * 64 + l) * 8);
      acc[0][nt] = MFMA(a0, bfr, acc[0][nt]);
      acc[1][nt] = MFMA(a1, bfr, acc[1][nt]);
    }
  }
  __syncthreads();  // xf dead; stage C into LDS
  int cl = l & 15, rq = (l >> 4) * 4;
  if (nstrip == 0) {  // k: scatter into A-frag-swizzled tile layout
#pragma unroll
    for (int mt = 0; mt < 2; mt++) {
      int a_mt = mstrip * 2 + mt;
#pragma unroll
      for (int nt = 0; nt < 8; nt++) {
        int col = nt * 16 + cl;
        int ks = col >> 5, hi = (col >> 3) & 3, j = col & 7;
        int base = ((a_mt * 4 + ks) * 64 + 16 * hi) * 8 + j;
#pragma unroll
        for (int rg = 0; rg < 4; rg++)
          kst[base + (rq + rg) * 8] = f2bf(acc[mt][nt][rg]);
      }
    }
  } else {  // v: row-major 64x128
#pragma unroll
    for (int mt = 0; mt < 2; mt++) {
      int row0 = mstrip * 32 + mt * 16;
#pragma unroll
      for (int nt = 0; nt < 8; nt++) {
        int col = nt * 16 + cl;
#pragma unroll
        for (int rg = 0; rg < 4; rg++)
          vst[(row0 + rq + rg) * 128 + col] = f2bf(acc[mt][nt][rg]);
      }
    }
  }
  __syncthreads();
  unsigned short* kg = kswz + (size_t)blockIdx.x * 8192;
  unsigned short* vg = vb + (size_t)rowbase * 128;
#pragma unroll
  for (int it = 0; it < 4; it++)
    *(sx8*)(kg + it * 2048 + tid * 8) = *(const sx8*)&kst[it * 2048 + tid * 8];
#pragma unroll
  for (int it = 0; it < 4; it++)
    *(sx8*)(vg + it * 2048 + tid * 8) = *(const sx8*)&vst[it * 2048 + tid * 8];
}

// ---------------- iter0 only: LN(slots) + q ----------------
__global__ __launch_bounds__(64) void k_slot_pre(
    const float* __restrict__ slots, const unsigned short* __restrict__ wq_b,
    float* __restrict__ slots_n, unsigned short* __restrict__ q_b) {
  __shared__ __align__(16) short xf[4 * 64 * 8];
  int l = threadIdx.x;
  int r = l & 15, seg = l >> 4;
  long rowbase = (long)blockIdx.x * 16;
  {
    const float* xp = slots + (rowbase + r) * 128 + seg * 32;
    float* snp = slots_n + (rowbase + r) * 128 + seg * 32;
    float v[32];
    float s = 0.f, s2 = 0.f;
#pragma unroll
    for (int i = 0; i < 8; i++) {
      fx4 t = *(const fx4*)(xp + i * 4);
      v[i * 4 + 0] = t.x; v[i * 4 + 1] = t.y; v[i * 4 + 2] = t.z; v[i * 4 + 3] = t.w;
      s += t.x + t.y + t.z + t.w;
      s2 += t.x * t.x + t.y * t.y + t.z * t.z + t.w * t.w;
    }
    s += __shfl_xor(s, 16, 64);  s += __shfl_xor(s, 32, 64);
    s2 += __shfl_xor(s2, 16, 64); s2 += __shfl_xor(s2, 32, 64);
    float mean = s * 0.0078125f;
    float var = s2 * 0.0078125f - mean * mean;
    float rstd = rsqrtf(var + 1e-5f);
#pragma unroll
    for (int i = 0; i < 8; i++) {
      fx4 t = {(v[i * 4 + 0] - mean) * rstd, (v[i * 4 + 1] - mean) * rstd,
               (v[i * 4 + 2] - mean) * rstd, (v[i * 4 + 3] - mean) * rstd};
      *(fx4*)(snp + i * 4) = t;
      v[i * 4 + 0] = t.x; v[i * 4 + 1] = t.y; v[i * 4 + 2] = t.z; v[i * 4 + 3] = t.w;
    }
#pragma unroll
    for (int q = 0; q < 4; q++) {
      sx8 t;
#pragma unroll
      for (int j = 0; j < 8; j++) t[j] = (short)f2bf(v[q * 8 + j]);
      *(sx8*)&xf[(seg * 64 + (r + 16 * q)) * 8] = t;
    }
  }
  __syncthreads();
  const fx4 z4 = {0.f, 0.f, 0.f, 0.f};
  fx4 acc[8];
#pragma unroll
  for (int nt = 0; nt < 8; nt++) acc[nt] = z4;
#pragma unroll
  for (int ks = 0; ks < 4; ks++) {
    sx8 a = *(const sx8*)&xf[(ks * 64 + l) * 8];
#pragma unroll
    for (int nt = 0; nt < 8; nt++) {
      sx8 bfr = *(const sx8*)(wq_b + (nt * 16 + (l & 15)) * 128 + ks * 32 + (l >> 4) * 8);
      acc[nt] = MFMA(a, bfr, acc[nt]);
    }
  }
  int cl = l & 15, rq = (l >> 4) * 4;
#pragma unroll
  for (int nt = 0; nt < 8; nt++)
#pragma unroll
    for (int rg = 0; rg < 4; rg++)
      q_b[(rowbase + rq + rg) * 128 + nt * 16 + cl] = f2bf(acc[nt][rg]);
}

// ---------------- attention ----------------
// grid = 128 batches * 16 chunks = 2048 blocks, 256 thr. Chunk = 256 rows; 1 tile of 64/wave.
__global__ __launch_bounds__(256) void k_attn(
    const unsigned short* __restrict__ kswz, const unsigned short* __restrict__ vb,
    const unsigned short* __restrict__ qb,
    float* __restrict__ upd_part, float* __restrict__ sattn_part) {
  __shared__ __align__(16) float abuf[4 * 1024];  // attn (64x16/wave), then updbuf overlay
  __shared__ float sattnbuf[4 * 8];
  int tid = threadIdx.x, w = tid >> 6, l = tid & 63;
  int b = blockIdx.x >> 4, c = blockIdx.x & 15;
  int tileg = b * 64 + c * 4 + w;
  const unsigned short* kt = kswz + (size_t)tileg * 8192;
  const unsigned short* vt = vb + (size_t)tileg * 8192;
  int s = l & 15, qd = (l >> 4) * 8;
  sx8 qf[4];
#pragma unroll
  for (int ks = 0; ks < 4; ks++) {
    if (s < 8) {
      qf[ks] = *(const sx8*)(qb + ((long)b * 8 + s) * 128 + ks * 32 + qd);
    } else {
      sx8 t;
#pragma unroll
      for (int j = 0; j < 8; j++) t[j] = 0;
      qf[ks] = t;
    }
  }
  const fx4 z4 = {0.f, 0.f, 0.f, 0.f};
  float sat_loc = 0.f;
  float ua[4][4] = {};
  int d0 = (l & 31) * 4, s0 = (l >> 5) * 4;
  float* attnw = abuf + w * 1024;
#pragma unroll
  for (int mt = 0; mt < 4; mt++) {
    fx4 cc = z4;
#pragma unroll
    for (int ks = 0; ks < 4; ks++) {
      sx8 a = *(const sx8*)(kt + ((mt * 4 + ks) * 64 + l) * 8);  // coalesced 1KB
      cc = MFMA(a, qf[ks], cc);
    }
#pragma unroll
    for (int rg = 0; rg < 4; rg++) {
      float lg = cc[rg];
      float mx = lg;
      mx = fmaxf(mx, __shfl_xor(mx, 1, 64));
      mx = fmaxf(mx, __shfl_xor(mx, 2, 64));
      mx = fmaxf(mx, __shfl_xor(mx, 4, 64));
      float p = __expf(lg - mx);
      float sm = p;
      sm += __shfl_xor(sm, 1, 64);
      sm += __shfl_xor(sm, 2, 64);
      sm += __shfl_xor(sm, 4, 64);
      float at = p / sm + 1e-8f;
      if (s < 8) sat_loc += at;
      attnw[(mt * 16 + (l >> 4) * 4 + rg) * 16 + s] = at;
    }
  }
#pragma unroll 2
  for (int n0 = 0; n0 < 64; n0 += 8) {
    ux4 vv[8]; fx4 at4[8];
#pragma unroll
    for (int u = 0; u < 8; u++) {
      vv[u] = *(const ux4*)(vt + (n0 + u) * 128 + d0);
      at4[u] = *(const fx4*)&attnw[(n0 + u) * 16 + s0];
    }
#pragma unroll
    for (int u = 0; u < 8; u++) {
      float v0 = bf2f(vv[u].x), v1 = bf2f(vv[u].y), v2 = bf2f(vv[u].z), v3 = bf2f(vv[u].w);
#pragma unroll
      for (int si = 0; si < 4; si++) {
        float av = at4[u][si];
        ua[si][0] += av * v0; ua[si][1] += av * v1;
        ua[si][2] += av * v2; ua[si][3] += av * v3;
      }
    }
  }
  // wave done reading attnw; reuse own 4KB as updbuf
#pragma unroll
  for (int si = 0; si < 4; si++) {
    fx4 tv = {ua[si][0], ua[si][1], ua[si][2], ua[si][3]};
    *(fx4*)&attnw[(s0 + si) * 128 + d0] = tv;
  }
  sat_loc += __shfl_xor(sat_loc, 16, 64);
  sat_loc += __shfl_xor(sat_loc, 32, 64);
  if (l < 8) sattnbuf[w * 8 + l] = sat_loc;
  __syncthreads();
  {
    int i = tid * 4;
    fx4 o = *(const fx4*)&abuf[i] + *(const fx4*)&abuf[1024 + i] +
            *(const fx4*)&abuf[2048 + i] + *(const fx4*)&abuf[3072 + i];
    *(fx4*)(upd_part + ((size_t)(b * 16 + c)) * 1024 + i) = o;
    if (tid < 8)
      sattn_part[(b * 16 + c) * 8 + tid] =
          sattnbuf[tid] + sattnbuf[8 + tid] + sattnbuf[16 + tid] + sattnbuf[24 + tid];
  }
}

// ---------------- GRU + MLP (+ fused next-iter LN+q) ----------------
// 64 blocks x 256 thr; 16 slot-rows (2 batches) per block.
__global__ __launch_bounds__(256) void k_slot_post(
    const float* __restrict__ upd_part, const float* __restrict__ sattn_part,
    float* __restrict__ slots_n,
    const unsigned short* __restrict__ wih_b, const unsigned short* __restrict__ whh_b,
    const float* __restrict__ b_ih, const float* __restrict__ b_hh,
    const unsigned short* __restrict__ w1_b, const float* __restrict__ b1,
    const unsigned short* __restrict__ w2_b, const float* __restrict__ b2,
    const unsigned short* __restrict__ wq_b,
    unsigned short* __restrict__ q_b, float* __restrict__ out_final, int final_flag) {
  __shared__ __align__(16) char smem[78336];
  float* gx = (float*)smem;                  // 24576 (16x384)
  float* gh = (float*)(smem + 24576);        // 24576
  float* xred = gx;                          // phase A overlay: 4*2048 floats = 32768
  short* xfr = (short*)(smem + 49152);       // 4096
  short* hfr = (short*)(smem + 53248);       // 4096
  short* ynf = (short*)(smem + 57344);       // 4096
  short* y1f = (short*)(smem + 61440);       // 8192
  float* snew = (float*)(smem + 69632);      // 16*132*4 = 8448
  float* satred = (float*)(smem + 78080);    // 4*16*4 = 256
  int tid = threadIdx.x, w = tid >> 6, l = tid & 63;
  int rowbase = blockIdx.x * 16;
  int r = l & 15, seg = l >> 4;
  {  // phase A: every wave reduces 4 chunks of upd partials
    int row = rowbase + r;
    int bb = row >> 3, ss = row & 7;
    float a[32];
#pragma unroll
    for (int i = 0; i < 32; i++) a[i] = 0.f;
    float satsum = 0.f;
#pragma unroll
    for (int ci = 0; ci < 4; ci++) {
      int ch = bb * 16 + w * 4 + ci;
      const float* up = upd_part + (size_t)ch * 1024 + ss * 128 + seg * 32;
#pragma unroll
      for (int i = 0; i < 8; i++) {
        fx4 t = *(const fx4*)(up + i * 4);
        a[i * 4 + 0] += t.x; a[i * 4 + 1] += t.y; a[i * 4 + 2] += t.z; a[i * 4 + 3] += t.w;
      }
      satsum += sattn_part[ch * 8 + ss];
    }
#pragma unroll
    for (int i = 0; i < 8; i++) {
      fx4 t = {a[i * 4], a[i * 4 + 1], a[i * 4 + 2], a[i * 4 + 3]};
      *(fx4*)&xred[w * 2048 + r * 128 + seg * 32 + i * 4] = t;
    }
    if (seg == 0) satred[w * 16 + r] = satsum;
  }
  __syncthreads();
  if (w == 0) {  // combine -> x A-frags
    float inv = 1.f / (satred[r] + satred[16 + r] + satred[32 + r] + satred[48 + r]);
    float a[32];
#pragma unroll
    for (int i = 0; i < 8; i++) {
      fx4 t = *(const fx4*)&xred[r * 128 + seg * 32 + i * 4];
      fx4 t1 = *(const fx4*)&xred[2048 + r * 128 + seg * 32 + i * 4];
      fx4 t2 = *(const fx4*)&xred[4096 + r * 128 + seg * 32 + i * 4];
      fx4 t3 = *(const fx4*)&xred[6144 + r * 128 + seg * 32 + i * 4];
      t = t + t1 + t2 + t3;
      a[i * 4 + 0] = t.x * inv; a[i * 4 + 1] = t.y * inv;
      a[i * 4 + 2] = t.z * inv; a[i * 4 + 3] = t.w * inv;
    }
#pragma unroll
    for (int q = 0; q < 4; q++) {
      sx8 t;
#pragma unroll
      for (int j = 0; j < 8; j++) t[j] = (short)f2bf(a[q * 8 + j]);
      *(sx8*)&xfr[(seg * 64 + (r + 16 * q)) * 8] = t;
    }
  } else if (w == 1) {  // h = slots_n -> A-frags
    const float* hp = slots_n + (long)(rowbase + r) * 128 + seg * 32;
#pragma unroll
    for (int q = 0; q < 4; q++) {
      fx4 t0 = *(const fx4*)(hp + q * 8);
      fx4 t1 = *(const fx4*)(hp + q * 8 + 4);
      sx8 t;
      t[0] = (short)f2bf(t0.x); t[1] = (short)f2bf(t0.y);
      t[2] = (short)f2bf(t0.z); t[3] = (short)f2bf(t0.w);
      t[4] = (short)f2bf(t1.x); t[5] = (short)f2bf(t1.y);
      t[6] = (short)f2bf(t1.z); t[7] = (short)f2bf(t1.w);
      *(sx8*)&hfr[(seg * 64 + (r + 16 * q)) * 8] = t;
    }
  }
  __syncthreads();
  const fx4 z4 = {0.f, 0.f, 0.f, 0.f};
  {  // GEMM1: gx = x@Wih^T, gh = h@Whh^T
    fx4 ax[6], ah[6];
#pragma unroll
    for (int j = 0; j < 6; j++) { ax[j] = z4; ah[j] = z4; }
#pragma unroll
    for (int ks = 0; ks < 4; ks++) {
      sx8 a_x = *(const sx8*)&xfr[(ks * 64 + l) * 8];
      sx8 a_h = *(const sx8*)&hfr[(ks * 64 + l) * 8];
#pragma unroll
      for (int j = 0; j < 6; j++) {
        int nt = w * 6 + j;
        sx8 bx = *(const sx8*)(wih_b + (nt * 16 + (l & 15)) * 128 + ks * 32 + (l >> 4) * 8);
        sx8 bh = *(const sx8*)(whh_b + (nt * 16 + (l & 15)) * 128 + ks * 32 + (l >> 4) * 8);
        ax[j] = MFMA(a_x, bx, ax[j]);
        ah[j] = MFMA(a_h, bh, ah[j]);
      }
    }
#pragma unroll
    for (int j = 0; j < 6; j++) {
      int col = (w * 6 + j) * 16 + (l & 15);
#pragma unroll
      for (int rg = 0; rg < 4; rg++) {
        int row = (l >> 4) * 4 + rg;
        gx[row * 384 + col] = ax[j][rg];
        gh[row * 384 + col] = ah[j][rg];
      }
    }
  }
  __syncthreads();
  {  // GRU gates
    int row = tid >> 4, j0 = (tid & 15) * 8;
#pragma unroll
    for (int j = j0; j < j0 + 8; j++) {
      float xr = gx[row * 384 + j] + b_ih[j];
      float xz = gx[row * 384 + 128 + j] + b_ih[128 + j];
      float xn = gx[row * 384 + 256 + j] + b_ih[256 + j];
      float hr = gh[row * 384 + j] + b_hh[j];
      float hz = gh[row * 384 + 128 + j] + b_hh[128 + j];
      float hn = gh[row * 384 + 256 + j] + b_hh[256 + j];
      float rr = 1.f / (1.f + __expf(-(xr + hr)));
      float zz = 1.f / (1.f + __expf(-(xz + hz)));
      float nn = tanhf(xn + rr * hn);
      float h = slots_n[(long)(rowbase + row) * 128 + j];
      snew[row * 132 + j] = (1.f - zz) * nn + zz * h;
    }
  }
  __syncthreads();
  if (w == 0) {  // LN(snew) -> ynf A-frags
    float v[32];
    float s = 0.f, s2 = 0.f;
#pragma unroll
    for (int i = 0; i < 32; i++) {
      float t = snew[r * 132 + seg * 32 + i];
      v[i] = t; s += t; s2 += t * t;
    }
    s += __shfl_xor(s, 16, 64);  s += __shfl_xor(s, 32, 64);
    s2 += __shfl_xor(s2, 16, 64); s2 += __shfl_xor(s2, 32, 64);
    float mean = s * 0.0078125f;
    float var = s2 * 0.0078125f - mean * mean;
    float rstd = rsqrtf(var + 1e-5f);
#pragma unroll
    for (int q = 0; q < 4; q++) {
      sx8 t;
#pragma unroll
      for (int j = 0; j < 8; j++) t[j] = (short)f2bf((v[q * 8 + j] - mean) * rstd);
      *(sx8*)&ynf[(seg * 64 + (r + 16 * q)) * 8] = t;
    }
  }
  __syncthreads();
  {  // GEMM2: y1 = relu(LN@W1^T + b1) -> A-frags for GEMM3
    fx4 y[4];
#pragma unroll
    for (int j = 0; j < 4; j++) y[j] = z4;
#pragma unroll
    for (int ks = 0; ks < 4; ks++) {
      sx8 a = *(const sx8*)&ynf[(ks * 64 + l) * 8];
#pragma unroll
      for (int j = 0; j < 4; j++) {
        int nt = w * 4 + j;
        sx8 bf = *(const sx8*)(w1_b + (nt * 16 + (l & 15)) * 128 + ks * 32 + (l >> 4) * 8);
        y[j] = MFMA(a, bf, y[j]);
      }
    }
#pragma unroll
    for (int j = 0; j < 4; j++) {
      int col = (w * 4 + j) * 16 + (l & 15);
      float bias = b1[col];
      int ks3 = col >> 5, qq = (col >> 3) & 3, jj = col & 7;
#pragma unroll
      for (int rg = 0; rg < 4; rg++) {
        float val = fmaxf(y[j][rg] + bias, 0.f);
        int m = (l >> 4) * 4 + rg;
        y1f[(ks3 * 64 + m + 16 * qq) * 8 + jj] = (short)f2bf(val);
      }
    }
  }
  __syncthreads();
  {  // GEMM3: snew += y1@W2^T + b2  (in-place; exclusive (row,col) per lane)
    fx4 zz2[2];
    zz2[0] = z4; zz2[1] = z4;
#pragma unroll
    for (int ks = 0; ks < 8; ks++) {
      sx8 a = *(const sx8*)&y1f[(ks * 64 + l) * 8];
#pragma unroll
      for (int j = 0; j < 2; j++) {
        sx8 bf = *(const sx8*)(w2_b + ((w * 2 + j) * 16 + (l & 15)) * 256 + ks * 32 + (l >> 4) * 8);
        zz2[j] = MFMA(a, bf, zz2[j]);
      }
    }
#pragma unroll
    for (int j = 0; j < 2; j++) {
      int col = (w * 2 + j) * 16 + (l & 15);
      float bias = b2[col];
#pragma unroll
      for (int rg = 0; rg < 4; rg++) {
        int row = (l >> 4) * 4 + rg;
        snew[row * 132 + col] += zz2[j][rg] + bias;
      }
    }
  }
  __syncthreads();
  if (final_flag) {  // write output fp32, coalesced
    int row = tid >> 4, c8 = (tid & 15) * 8;
    fx4 t0 = *(const fx4*)&snew[row * 132 + c8];
    fx4 t1 = *(const fx4*)&snew[row * 132 + c8 + 4];
    *(fx4*)(out_final + (long)(rowbase + row) * 128 + c8) = t0;
    *(fx4*)(out_final + (long)(rowbase + row) * 128 + c8 + 4) = t1;
    return;
  }
  // fused next-iter: LN(new slots) -> slots_n (in place) + q
  if (w == 0) {
    float v[32];
    float s = 0.f, s2 = 0.f;
#pragma unroll
    for (int i = 0; i < 32; i++) {
      float t = snew[r * 132 + seg * 32 + i];
      v[i] = t; s += t; s2 += t * t;
    }
    s += __shfl_xor(s, 16, 64);  s += __shfl_xor(s, 32, 64);
    s2 += __shfl_xor(s2, 16, 64); s2 += __shfl_xor(s2, 32, 64);
    float mean = s * 0.0078125f;
    float var = s2 * 0.0078125f - mean * mean;
    float rstd = rsqrtf(var + 1e-5f);
    float* snp = slots_n + (long)(rowbase + r) * 128 + seg * 32;
#pragma unroll
    for (int i = 0; i < 8; i++) {
      fx4 t = {(v[i * 4 + 0] - mean) * rstd, (v[i * 4 + 1] - mean) * rstd,
               (v[i * 4 + 2] - mean) * rstd, (v[i * 4 + 3] - mean) * rstd};
      *(fx4*)(snp + i * 4) = t;
      v[i * 4 + 0] = t.x; v[i * 4 + 1] = t.y; v[i * 4 + 2] = t.z; v[i * 4 + 3] = t.w;
    }
#pragma unroll
    for (int q = 0; q < 4; q++) {
      sx8 t;
#pragma unroll
      for (int j = 0; j < 8; j++) t[j] = (short)f2bf(v[q * 8 + j]);
      *(sx8*)&ynf[(seg * 64 + (r + 16 * q)) * 8] = t;
    }
  }
  __syncthreads();
  {  // q GEMM: wave w computes nt = w*2, w*2+1
    fx4 acc2[2];
    acc2[0] = z4; acc2[1] = z4;
#pragma unroll
    for (int ks = 0; ks < 4; ks++) {
      sx8 a = *(const sx8*)&ynf[(ks * 64 + l) * 8];
#pragma unroll
      for (int j = 0; j < 2; j++) {
        int nt = w * 2 + j;
        sx8 bf = *(const sx8*)(wq_b + (nt * 16 + (l & 15)) * 128 + ks * 32 + (l >> 4) * 8);
        acc2[j] = MFMA(a, bf, acc2[j]);
      }
    }
    int cl = l & 15, rq = (l >> 4) * 4;
#pragma unroll
    for (int j = 0; j < 2; j++) {
      int nt = w * 2 + j;
#pragma unroll
      for (int rg = 0; rg < 4; rg++)
        q_b[(long)(rowbase + rq + rg) * 128 + nt * 16 + cl] = f2bf(acc2[j][rg]);
    }
  }
}

extern "C" void kernel_launch(void* const* d_in, const int* in_sizes, int n_in,
                              void* d_out, int out_size, void* d_ws, size_t ws_size,
                              hipStream_t stream) {
  (void)in_sizes; (void)n_in; (void)out_size; (void)ws_size;
  const float* x = (const float*)d_in[0];
  const float* noise = (const float*)d_in[1];
  const float* mu = (const float*)d_in[2];
  const float* lsig = (const float*)d_in[3];
  const float* Wq = (const float*)d_in[4];
  const float* Wk = (const float*)d_in[5];
  const float* Wv = (const float*)d_in[6];
  const float* Wih = (const float*)d_in[7];
  const float* Whh = (const float*)d_in[8];
  const float* b_ih = (const float*)d_in[9];
  const float* b_hh = (const float*)d_in[10];
  const float* W1 = (const float*)d_in[11];
  const float* b1 = (const float*)d_in[12];
  const float* W2 = (const float*)d_in[13];
  const float* b2 = (const float*)d_in[14];

  char* ws = (char*)d_ws;
  size_t off = 0;
  auto take = [&](size_t bytes) {
    char* p = ws + off;
    off += (bytes + 255) & ~(size_t)255;
    return p;
  };
  unsigned short* kswz = (unsigned short*)take(134217728);    // k bf16, tile-swizzled
  unsigned short* vb = (unsigned short*)take(134217728);      // v bf16 row-major
  unsigned short* wswz = (unsigned short*)take(65536);
  unsigned short* wq_b = (unsigned short*)take(32768);
  unsigned short* wih_b = (unsigned short*)take(98304);
  unsigned short* whh_b = (unsigned short*)take(98304);
  unsigned short* w1_b = (unsigned short*)take(65536);
  unsigned short* w2_b = (unsigned short*)take(65536);
  float* slots = (float*)take(524288);
  float* slots_n = (float*)take(524288);
  unsigned short* q_b = (unsigned short*)take(262144);
  float* upd_part = (float*)take(8388608);    // (B,16,8,128) fp32
  float* sattn_part = (float*)take(65536);    // (B,16,8)

  k_prep<<<1344, 256, 0, stream>>>(noise, mu, lsig, Wq, Wk, Wv, Wih, Whh, W1, W2,
                                   slots, wswz, wq_b, wih_b, whh_b, w1_b, w2_b);
  k_lnkv<<<8192, 256, 0, stream>>>(x, wswz, kswz, vb);
  k_slot_pre<<<64, 64, 0, stream>>>(slots, wq_b, slots_n, q_b);
  for (int it = 0; it < 3; it++) {
    k_attn<<<2048, 256, 0, stream>>>(kswz, vb, q_b, upd_part, sattn_part);
    k_slot_post<<<64, 256, 0, stream>>>(upd_part, sattn_part, slots_n, wih_b, whh_b,
                                        b_ih, b_hh, w1_b, b1, w2_b, b2, wq_b,
                                        q_b, (float*)d_out, (it == 2) ? 1 : 0);
  }
}

// Round 3
// 608.900 us; speedup vs baseline: 1.1742x; 1.1742x over previous
//
#include <hip/hip_runtime.h>
#include <math.h>

// B=128, N=4096, Din=128, D=128, S(slots)=8, H=256, 3 iterations.
// Algebraic folds: logits = xn @ q2^T with q2 = slots_n @ Wqk, Wqk = scale*Wq^T@Wk.
// gx = raw @ Wihv^T with raw = attn^T @ xn (per-chunk partials), Wihv = Wih@Wv.
// k and v are never materialized; only ln_x (bf16, row-major) is stored.
// MFMA 16x16x32 bf16 layouts (verified):
//   C/D: col = lane&15, row = (lane>>4)*4 + reg
//   A  : A[m = lane&15][k = (lane>>4)*8 + j]
//   B  : B[k = (lane>>4)*8 + j][n = lane&15]  (row-major [N][K] source)

typedef __attribute__((ext_vector_type(4))) float fx4;
typedef __attribute__((ext_vector_type(8))) short sx8;
typedef __attribute__((ext_vector_type(8))) __bf16 bfx8;
typedef __attribute__((ext_vector_type(4))) unsigned short ux4;

static __device__ __forceinline__ fx4 MFMA(sx8 a, sx8 b, fx4 c) {
  return __builtin_amdgcn_mfma_f32_16x16x32_bf16(
      __builtin_bit_cast(bfx8, a), __builtin_bit_cast(bfx8, b), c, 0, 0, 0);
}

static __device__ __forceinline__ unsigned short f2bf(float f) {
  union { float f; unsigned u; } x; x.f = f;
  unsigned r = x.u + 0x7fffu + ((x.u >> 16) & 1u);  // RNE
  return (unsigned short)(r >> 16);
}
static __device__ __forceinline__ float bf2f(unsigned short u) {
  union { unsigned u; float f; } x; x.u = ((unsigned)u) << 16; return x.f;
}

// ---------------- fold: Wqk = scale*Wq^T@Wk (fp32), Wihv = Wih@Wv (fp32) ----------------
__global__ __launch_bounds__(256) void k_fold(
    const float* __restrict__ Wq, const float* __restrict__ Wk,
    const float* __restrict__ Wih, const float* __restrict__ Wv,
    float* __restrict__ Wqk, float* __restrict__ Wihv) {
  int idx = blockIdx.x * 256 + threadIdx.x;
  if (idx < 16384) {  // Wqk[e,c] = scale * sum_d Wq[d,e]*Wk[d,c]
    int e = idx >> 7, c = idx & 127;
    float s = 0.f;
#pragma unroll 4
    for (int d = 0; d < 128; d++) s += Wq[d * 128 + e] * Wk[d * 128 + c];
    Wqk[idx] = s * 0.08838834764831845f;
    return;
  }
  idx -= 16384;
  if (idx < 49152) {  // Wihv[g,c] = sum_d Wih[g,d]*Wv[d,c]
    int g = idx >> 7, c = idx & 127;
    float s = 0.f;
#pragma unroll 4
    for (int d = 0; d < 128; d++) s += Wih[g * 128 + d] * Wv[d * 128 + c];
    Wihv[idx] = s;
  }
}

// ---------------- pack: slots init + bf16 weight tables ----------------
__global__ __launch_bounds__(256) void k_pack(
    const float* __restrict__ noise, const float* __restrict__ mu,
    const float* __restrict__ lsig, const float* __restrict__ Wqk,
    const float* __restrict__ Wihv, const float* __restrict__ Whh,
    const float* __restrict__ W1, const float* __restrict__ W2,
    float* __restrict__ slots, unsigned short* __restrict__ wqk_b,
    unsigned short* __restrict__ wihv_b, unsigned short* __restrict__ whh_b,
    unsigned short* __restrict__ w1_b, unsigned short* __restrict__ w2_b) {
  int idx = blockIdx.x * 256 + threadIdx.x;
  if (idx < 131072) {
    int d = idx & 127;
    slots[idx] = mu[d] + expf(lsig[d]) * noise[idx];
    return;
  }
  idx -= 131072;
  if (idx < 16384) {  // wqk_b row-major [n=c][k=e] <- Wqk[e,c]
    wqk_b[idx] = f2bf(Wqk[(idx & 127) * 128 + (idx >> 7)]);
    return;
  }
  idx -= 16384;
  if (idx < 49152) { wihv_b[idx] = f2bf(Wihv[idx]); return; }
  idx -= 49152;
  if (idx < 49152) { whh_b[idx] = f2bf(Whh[idx]); return; }
  idx -= 49152;
  if (idx < 32768) { w1_b[idx] = f2bf(W1[idx]); return; }
  idx -= 32768;
  w2_b[idx] = f2bf(W2[idx]);
}

// ---------------- LN(x) -> bf16 row-major, pure streaming ----------------
// 256 thr = 4 waves, 2 rows/wave (32 lanes per row, fx4 each).
__global__ __launch_bounds__(256) void k_ln(
    const float* __restrict__ x, unsigned short* __restrict__ ln16) {
  long row = (long)blockIdx.x * 8 + (threadIdx.x >> 5);
  int c4 = (threadIdx.x & 31) * 4;
  fx4 t = *(const fx4*)(x + row * 128 + c4);
  float s = t.x + t.y + t.z + t.w;
  float s2 = t.x * t.x + t.y * t.y + t.z * t.z + t.w * t.w;
#pragma unroll
  for (int m = 1; m < 32; m <<= 1) {
    s += __shfl_xor(s, m, 64);
    s2 += __shfl_xor(s2, m, 64);
  }
  float mean = s * 0.0078125f;
  float rstd = rsqrtf(s2 * 0.0078125f - mean * mean + 1e-5f);
  ux4 o;
  o.x = f2bf((t.x - mean) * rstd);
  o.y = f2bf((t.y - mean) * rstd);
  o.z = f2bf((t.z - mean) * rstd);
  o.w = f2bf((t.w - mean) * rstd);
  *(ux4*)(ln16 + row * 128 + c4) = o;
}

// ---------------- iter0 only: LN(slots) + q2 = slots_n @ Wqk ----------------
__global__ __launch_bounds__(64) void k_slot_pre(
    const float* __restrict__ slots, const unsigned short* __restrict__ wqk_b,
    float* __restrict__ slots_n, unsigned short* __restrict__ q2_b) {
  __shared__ __align__(16) short xf[4 * 64 * 8];
  int l = threadIdx.x;
  int r = l & 15, seg = l >> 4;
  long rowbase = (long)blockIdx.x * 16;
  {
    const float* xp = slots + (rowbase + r) * 128 + seg * 32;
    float* snp = slots_n + (rowbase + r) * 128 + seg * 32;
    float v[32];
    float s = 0.f, s2 = 0.f;
#pragma unroll
    for (int i = 0; i < 8; i++) {
      fx4 t = *(const fx4*)(xp + i * 4);
      v[i * 4 + 0] = t.x; v[i * 4 + 1] = t.y; v[i * 4 + 2] = t.z; v[i * 4 + 3] = t.w;
      s += t.x + t.y + t.z + t.w;
      s2 += t.x * t.x + t.y * t.y + t.z * t.z + t.w * t.w;
    }
    s += __shfl_xor(s, 16, 64);  s += __shfl_xor(s, 32, 64);
    s2 += __shfl_xor(s2, 16, 64); s2 += __shfl_xor(s2, 32, 64);
    float mean = s * 0.0078125f;
    float var = s2 * 0.0078125f - mean * mean;
    float rstd = rsqrtf(var + 1e-5f);
#pragma unroll
    for (int i = 0; i < 8; i++) {
      fx4 t = {(v[i * 4 + 0] - mean) * rstd, (v[i * 4 + 1] - mean) * rstd,
               (v[i * 4 + 2] - mean) * rstd, (v[i * 4 + 3] - mean) * rstd};
      *(fx4*)(snp + i * 4) = t;
      v[i * 4 + 0] = t.x; v[i * 4 + 1] = t.y; v[i * 4 + 2] = t.z; v[i * 4 + 3] = t.w;
    }
#pragma unroll
    for (int q = 0; q < 4; q++) {
      sx8 t;
#pragma unroll
      for (int j = 0; j < 8; j++) t[j] = (short)f2bf(v[q * 8 + j]);
      *(sx8*)&xf[(seg * 64 + (r + 16 * q)) * 8] = t;
    }
  }
  __syncthreads();
  const fx4 z4 = {0.f, 0.f, 0.f, 0.f};
  fx4 acc[8];
#pragma unroll
  for (int nt = 0; nt < 8; nt++) acc[nt] = z4;
#pragma unroll
  for (int ks = 0; ks < 4; ks++) {
    sx8 a = *(const sx8*)&xf[(ks * 64 + l) * 8];
#pragma unroll
    for (int nt = 0; nt < 8; nt++) {
      sx8 bfr = *(const sx8*)(wqk_b + (nt * 16 + (l & 15)) * 128 + ks * 32 + (l >> 4) * 8);
      acc[nt] = MFMA(a, bfr, acc[nt]);
    }
  }
  int cl = l & 15, rq = (l >> 4) * 4;
#pragma unroll
  for (int nt = 0; nt < 8; nt++)
#pragma unroll
    for (int rg = 0; rg < 4; rg++)
      q2_b[(rowbase + rq + rg) * 128 + nt * 16 + cl] = f2bf(acc[nt][rg]);
}

// ---------------- attention: logits = xn@q2^T, softmax, raw = attn^T@xn ----------------
// grid = 128 batches * 16 chunks = 2048 blocks, 256 thr; 1 tile of 64 rows per wave.
__global__ __launch_bounds__(256) void k_attn(
    const unsigned short* __restrict__ ln16, const unsigned short* __restrict__ q2b,
    float* __restrict__ upd_part, float* __restrict__ sattn_part) {
  __shared__ __align__(16) float abuf[4 * 1024];
  __shared__ float sattnbuf[4 * 8];
  int tid = threadIdx.x, w = tid >> 6, l = tid & 63;
  int b = blockIdx.x >> 4, c = blockIdx.x & 15;
  long base = (long)b * 4096 + (c * 4 + w) * 64;
  const unsigned short* xt = ln16 + base * 128;
  int s = l & 15, qd = (l >> 4) * 8;
  sx8 qf[4];
#pragma unroll
  for (int ks = 0; ks < 4; ks++) {
    if (s < 8) {
      qf[ks] = *(const sx8*)(q2b + ((long)b * 8 + s) * 128 + ks * 32 + qd);
    } else {
      sx8 t;
#pragma unroll
      for (int j = 0; j < 8; j++) t[j] = 0;
      qf[ks] = t;
    }
  }
  // A-frags straight from row-major ln_x: 16 independent 16B loads
  sx8 a[4][4];
#pragma unroll
  for (int mt = 0; mt < 4; mt++)
#pragma unroll
    for (int ks = 0; ks < 4; ks++)
      a[mt][ks] = *(const sx8*)(xt + (mt * 16 + s) * 128 + ks * 32 + qd);
  const fx4 z4 = {0.f, 0.f, 0.f, 0.f};
  float sat_loc = 0.f;
  float ua[4][4] = {};
  int d0 = (l & 31) * 4, s0 = (l >> 5) * 4;
  float* attnw = abuf + w * 1024;
#pragma unroll
  for (int mt = 0; mt < 4; mt++) {
    fx4 cc = z4;
#pragma unroll
    for (int ks = 0; ks < 4; ks++) cc = MFMA(a[mt][ks], qf[ks], cc);
#pragma unroll
    for (int rg = 0; rg < 4; rg++) {
      float lg = cc[rg];
      float mx = lg;
      mx = fmaxf(mx, __shfl_xor(mx, 1, 64));
      mx = fmaxf(mx, __shfl_xor(mx, 2, 64));
      mx = fmaxf(mx, __shfl_xor(mx, 4, 64));
      float p = __expf(lg - mx);
      float sm = p;
      sm += __shfl_xor(sm, 1, 64);
      sm += __shfl_xor(sm, 2, 64);
      sm += __shfl_xor(sm, 4, 64);
      float at = p / sm + 1e-8f;
      if (s < 8) sat_loc += at;
      attnw[(mt * 16 + (l >> 4) * 4 + rg) * 16 + s] = at;
    }
  }
  // raw accumulation: re-read xn rows (L1/L2-hot), fp32 FMA
#pragma unroll 2
  for (int n0 = 0; n0 < 64; n0 += 8) {
    ux4 vv[8]; fx4 at4[8];
#pragma unroll
    for (int u = 0; u < 8; u++) {
      vv[u] = *(const ux4*)(xt + (n0 + u) * 128 + d0);
      at4[u] = *(const fx4*)&attnw[(n0 + u) * 16 + s0];
    }
#pragma unroll
    for (int u = 0; u < 8; u++) {
      float v0 = bf2f(vv[u].x), v1 = bf2f(vv[u].y), v2 = bf2f(vv[u].z), v3 = bf2f(vv[u].w);
#pragma unroll
      for (int si = 0; si < 4; si++) {
        float av = at4[u][si];
        ua[si][0] += av * v0; ua[si][1] += av * v1;
        ua[si][2] += av * v2; ua[si][3] += av * v3;
      }
    }
  }
#pragma unroll
  for (int si = 0; si < 4; si++) {
    fx4 tv = {ua[si][0], ua[si][1], ua[si][2], ua[si][3]};
    *(fx4*)&attnw[(s0 + si) * 128 + d0] = tv;
  }
  sat_loc += __shfl_xor(sat_loc, 16, 64);
  sat_loc += __shfl_xor(sat_loc, 32, 64);
  if (l < 8) sattnbuf[w * 8 + l] = sat_loc;
  __syncthreads();
  {
    int i = tid * 4;
    fx4 o = *(const fx4*)&abuf[i] + *(const fx4*)&abuf[1024 + i] +
            *(const fx4*)&abuf[2048 + i] + *(const fx4*)&abuf[3072 + i];
    *(fx4*)(upd_part + ((size_t)(b * 16 + c)) * 1024 + i) = o;
    if (tid < 8)
      sattn_part[(b * 16 + c) * 8 + tid] =
          sattnbuf[tid] + sattnbuf[8 + tid] + sattnbuf[16 + tid] + sattnbuf[24 + tid];
  }
}

// ---------------- GRU + MLP (+ fused next-iter LN+q2) ----------------
// 64 blocks x 256 thr; 16 slot-rows (2 batches) per block.
__global__ __launch_bounds__(256) void k_slot_post(
    const float* __restrict__ upd_part, const float* __restrict__ sattn_part,
    float* __restrict__ slots_n,
    const unsigned short* __restrict__ wihv_b, const unsigned short* __restrict__ whh_b,
    const float* __restrict__ b_ih, const float* __restrict__ b_hh,
    const unsigned short* __restrict__ w1_b, const float* __restrict__ b1,
    const unsigned short* __restrict__ w2_b, const float* __restrict__ b2,
    const unsigned short* __restrict__ wqk_b,
    unsigned short* __restrict__ q2_b, float* __restrict__ out_final, int final_flag) {
  __shared__ __align__(16) char smem[78336];
  float* gx = (float*)smem;                  // 24576 (16x384)
  float* gh = (float*)(smem + 24576);        // 24576
  float* xred = gx;                          // phase A overlay: 4*2048 floats
  short* xfr = (short*)(smem + 49152);       // 4096
  short* hfr = (short*)(smem + 53248);       // 4096
  short* ynf = (short*)(smem + 57344);       // 4096
  short* y1f = (short*)(smem + 61440);       // 8192
  float* snew = (float*)(smem + 69632);      // 16*132*4 = 8448
  float* satred = (float*)(smem + 78080);    // 256
  int tid = threadIdx.x, w = tid >> 6, l = tid & 63;
  int rowbase = blockIdx.x * 16;
  int r = l & 15, seg = l >> 4;
  {  // phase A: every wave reduces 4 chunks of raw partials
    int row = rowbase + r;
    int bb = row >> 3, ss = row & 7;
    float a[32];
#pragma unroll
    for (int i = 0; i < 32; i++) a[i] = 0.f;
    float satsum = 0.f;
#pragma unroll
    for (int ci = 0; ci < 4; ci++) {
      int ch = bb * 16 + w * 4 + ci;
      const float* up = upd_part + (size_t)ch * 1024 + ss * 128 + seg * 32;
#pragma unroll
      for (int i = 0; i < 8; i++) {
        fx4 t = *(const fx4*)(up + i * 4);
        a[i * 4 + 0] += t.x; a[i * 4 + 1] += t.y; a[i * 4 + 2] += t.z; a[i * 4 + 3] += t.w;
      }
      satsum += sattn_part[ch * 8 + ss];
    }
#pragma unroll
    for (int i = 0; i < 8; i++) {
      fx4 t = {a[i * 4], a[i * 4 + 1], a[i * 4 + 2], a[i * 4 + 3]};
      *(fx4*)&xred[w * 2048 + r * 128 + seg * 32 + i * 4] = t;
    }
    if (seg == 0) satred[w * 16 + r] = satsum;
  }
  __syncthreads();
  if (w == 0) {  // combine -> raw_scaled A-frags
    float inv = 1.f / (satred[r] + satred[16 + r] + satred[32 + r] + satred[48 + r]);
    float a[32];
#pragma unroll
    for (int i = 0; i < 8; i++) {
      fx4 t = *(const fx4*)&xred[r * 128 + seg * 32 + i * 4];
      fx4 t1 = *(const fx4*)&xred[2048 + r * 128 + seg * 32 + i * 4];
      fx4 t2 = *(const fx4*)&xred[4096 + r * 128 + seg * 32 + i * 4];
      fx4 t3 = *(const fx4*)&xred[6144 + r * 128 + seg * 32 + i * 4];
      t = t + t1 + t2 + t3;
      a[i * 4 + 0] = t.x * inv; a[i * 4 + 1] = t.y * inv;
      a[i * 4 + 2] = t.z * inv; a[i * 4 + 3] = t.w * inv;
    }
#pragma unroll
    for (int q = 0; q < 4; q++) {
      sx8 t;
#pragma unroll
      for (int j = 0; j < 8; j++) t[j] = (short)f2bf(a[q * 8 + j]);
      *(sx8*)&xfr[(seg * 64 + (r + 16 * q)) * 8] = t;
    }
  } else if (w == 1) {  // h = slots_n -> A-frags
    const float* hp = slots_n + (long)(rowbase + r) * 128 + seg * 32;
#pragma unroll
    for (int q = 0; q < 4; q++) {
      fx4 t0 = *(const fx4*)(hp + q * 8);
      fx4 t1 = *(const fx4*)(hp + q * 8 + 4);
      sx8 t;
      t[0] = (short)f2bf(t0.x); t[1] = (short)f2bf(t0.y);
      t[2] = (short)f2bf(t0.z); t[3] = (short)f2bf(t0.w);
      t[4] = (short)f2bf(t1.x); t[5] = (short)f2bf(t1.y);
      t[6] = (short)f2bf(t1.z); t[7] = (short)f2bf(t1.w);
      *(sx8*)&hfr[(seg * 64 + (r + 16 * q)) * 8] = t;
    }
  }
  __syncthreads();
  const fx4 z4 = {0.f, 0.f, 0.f, 0.f};
  {  // GEMM1: gx = raw_scaled@Wihv^T, gh = h@Whh^T
    fx4 ax[6], ah[6];
#pragma unroll
    for (int j = 0; j < 6; j++) { ax[j] = z4; ah[j] = z4; }
#pragma unroll
    for (int ks = 0; ks < 4; ks++) {
      sx8 a_x = *(const sx8*)&xfr[(ks * 64 + l) * 8];
      sx8 a_h = *(const sx8*)&hfr[(ks * 64 + l) * 8];
#pragma unroll
      for (int j = 0; j < 6; j++) {
        int nt = w * 6 + j;
        sx8 bx = *(const sx8*)(wihv_b + (nt * 16 + (l & 15)) * 128 + ks * 32 + (l >> 4) * 8);
        sx8 bh = *(const sx8*)(whh_b + (nt * 16 + (l & 15)) * 128 + ks * 32 + (l >> 4) * 8);
        ax[j] = MFMA(a_x, bx, ax[j]);
        ah[j] = MFMA(a_h, bh, ah[j]);
      }
    }
#pragma unroll
    for (int j = 0; j < 6; j++) {
      int col = (w * 6 + j) * 16 + (l & 15);
#pragma unroll
      for (int rg = 0; rg < 4; rg++) {
        int row = (l >> 4) * 4 + rg;
        gx[row * 384 + col] = ax[j][rg];
        gh[row * 384 + col] = ah[j][rg];
      }
    }
  }
  __syncthreads();
  {  // GRU gates
    int row = tid >> 4, j0 = (tid & 15) * 8;
#pragma unroll
    for (int j = j0; j < j0 + 8; j++) {
      float xr = gx[row * 384 + j] + b_ih[j];
      float xz = gx[row * 384 + 128 + j] + b_ih[128 + j];
      float xn = gx[row * 384 + 256 + j] + b_ih[256 + j];
      float hr = gh[row * 384 + j] + b_hh[j];
      float hz = gh[row * 384 + 128 + j] + b_hh[128 + j];
      float hn = gh[row * 384 + 256 + j] + b_hh[256 + j];
      float rr = 1.f / (1.f + __expf(-(xr + hr)));
      float zz = 1.f / (1.f + __expf(-(xz + hz)));
      float nn = tanhf(xn + rr * hn);
      float h = slots_n[(long)(rowbase + row) * 128 + j];
      snew[row * 132 + j] = (1.f - zz) * nn + zz * h;
    }
  }
  __syncthreads();
  if (w == 0) {  // LN(snew) -> ynf A-frags
    float v[32];
    float s = 0.f, s2 = 0.f;
#pragma unroll
    for (int i = 0; i < 32; i++) {
      float t = snew[r * 132 + seg * 32 + i];
      v[i] = t; s += t; s2 += t * t;
    }
    s += __shfl_xor(s, 16, 64);  s += __shfl_xor(s, 32, 64);
    s2 += __shfl_xor(s2, 16, 64); s2 += __shfl_xor(s2, 32, 64);
    float mean = s * 0.0078125f;
    float var = s2 * 0.0078125f - mean * mean;
    float rstd = rsqrtf(var + 1e-5f);
#pragma unroll
    for (int q = 0; q < 4; q++) {
      sx8 t;
#pragma unroll
      for (int j = 0; j < 8; j++) t[j] = (short)f2bf((v[q * 8 + j] - mean) * rstd);
      *(sx8*)&ynf[(seg * 64 + (r + 16 * q)) * 8] = t;
    }
  }
  __syncthreads();
  {  // GEMM2: y1 = relu(LN@W1^T + b1) -> A-frags for GEMM3
    fx4 y[4];
#pragma unroll
    for (int j = 0; j < 4; j++) y[j] = z4;
#pragma unroll
    for (int ks = 0; ks < 4; ks++) {
      sx8 a = *(const sx8*)&ynf[(ks * 64 + l) * 8];
#pragma unroll
      for (int j = 0; j < 4; j++) {
        int nt = w * 4 + j;
        sx8 bf = *(const sx8*)(w1_b + (nt * 16 + (l & 15)) * 128 + ks * 32 + (l >> 4) * 8);
        y[j] = MFMA(a, bf, y[j]);
      }
    }
#pragma unroll
    for (int j = 0; j < 4; j++) {
      int col = (w * 4 + j) * 16 + (l & 15);
      float bias = b1[col];
      int ks3 = col >> 5, qq = (col >> 3) & 3, jj = col & 7;
#pragma unroll
      for (int rg = 0; rg < 4; rg++) {
        float val = fmaxf(y[j][rg] + bias, 0.f);
        int m = (l >> 4) * 4 + rg;
        y1f[(ks3 * 64 + m + 16 * qq) * 8 + jj] = (short)f2bf(val);
      }
    }
  }
  __syncthreads();
  {  // GEMM3: snew += y1@W2^T + b2
    fx4 zz2[2];
    zz2[0] = z4; zz2[1] = z4;
#pragma unroll
    for (int ks = 0; ks < 8; ks++) {
      sx8 a = *(const sx8*)&y1f[(ks * 64 + l) * 8];
#pragma unroll
      for (int j = 0; j < 2; j++) {
        sx8 bf = *(const sx8*)(w2_b + ((w * 2 + j) * 16 + (l & 15)) * 256 + ks * 32 + (l >> 4) * 8);
        zz2[j] = MFMA(a, bf, zz2[j]);
      }
    }
#pragma unroll
    for (int j = 0; j < 2; j++) {
      int col = (w * 2 + j) * 16 + (l & 15);
      float bias = b2[col];
#pragma unroll
      for (int rg = 0; rg < 4; rg++) {
        int row = (l >> 4) * 4 + rg;
        snew[row * 132 + col] += zz2[j][rg] + bias;
      }
    }
  }
  __syncthreads();
  if (final_flag) {
    int row = tid >> 4, c8 = (tid & 15) * 8;
    fx4 t0 = *(const fx4*)&snew[row * 132 + c8];
    fx4 t1 = *(const fx4*)&snew[row * 132 + c8 + 4];
    *(fx4*)(out_final + (long)(rowbase + row) * 128 + c8) = t0;
    *(fx4*)(out_final + (long)(rowbase + row) * 128 + c8 + 4) = t1;
    return;
  }
  // fused next-iter: LN(new slots) -> slots_n + q2
  if (w == 0) {
    float v[32];
    float s = 0.f, s2 = 0.f;
#pragma unroll
    for (int i = 0; i < 32; i++) {
      float t = snew[r * 132 + seg * 32 + i];
      v[i] = t; s += t; s2 += t * t;
    }
    s += __shfl_xor(s, 16, 64);  s += __shfl_xor(s, 32, 64);
    s2 += __shfl_xor(s2, 16, 64); s2 += __shfl_xor(s2, 32, 64);
    float mean = s * 0.0078125f;
    float var = s2 * 0.0078125f - mean * mean;
    float rstd = rsqrtf(var + 1e-5f);
    float* snp = slots_n + (long)(rowbase + r) * 128 + seg * 32;
#pragma unroll
    for (int i = 0; i < 8; i++) {
      fx4 t = {(v[i * 4 + 0] - mean) * rstd, (v[i * 4 + 1] - mean) * rstd,
               (v[i * 4 + 2] - mean) * rstd, (v[i * 4 + 3] - mean) * rstd};
      *(fx4*)(snp + i * 4) = t;
      v[i * 4 + 0] = t.x; v[i * 4 + 1] = t.y; v[i * 4 + 2] = t.z; v[i * 4 + 3] = t.w;
    }
#pragma unroll
    for (int q = 0; q < 4; q++) {
      sx8 t;
#pragma unroll
      for (int j = 0; j < 8; j++) t[j] = (short)f2bf(v[q * 8 + j]);
      *(sx8*)&ynf[(seg * 64 + (r + 16 * q)) * 8] = t;
    }
  }
  __syncthreads();
  {  // q2 GEMM: wave w computes nt = w*2, w*2+1
    fx4 acc2[2];
    acc2[0] = z4; acc2[1] = z4;
#pragma unroll
    for (int ks = 0; ks < 4; ks++) {
      sx8 a = *(const sx8*)&ynf[(ks * 64 + l) * 8];
#pragma unroll
      for (int j = 0; j < 2; j++) {
        int nt = w * 2 + j;
        sx8 bf = *(const sx8*)(wqk_b + (nt * 16 + (l & 15)) * 128 + ks * 32 + (l >> 4) * 8);
        acc2[j] = MFMA(a, bf, acc2[j]);
      }
    }
    int cl = l & 15, rq = (l >> 4) * 4;
#pragma unroll
    for (int j = 0; j < 2; j++) {
      int nt = w * 2 + j;
#pragma unroll
      for (int rg = 0; rg < 4; rg++)
        q2_b[(long)(rowbase + rq + rg) * 128 + nt * 16 + cl] = f2bf(acc2[j][rg]);
    }
  }
}

extern "C" void kernel_launch(void* const* d_in, const int* in_sizes, int n_in,
                              void* d_out, int out_size, void* d_ws, size_t ws_size,
                              hipStream_t stream) {
  (void)in_sizes; (void)n_in; (void)out_size; (void)ws_size;
  const float* x = (const float*)d_in[0];
  const float* noise = (const float*)d_in[1];
  const float* mu = (const float*)d_in[2];
  const float* lsig = (const float*)d_in[3];
  const float* Wq = (const float*)d_in[4];
  const float* Wk = (const float*)d_in[5];
  const float* Wv = (const float*)d_in[6];
  const float* Wih = (const float*)d_in[7];
  const float* Whh = (const float*)d_in[8];
  const float* b_ih = (const float*)d_in[9];
  const float* b_hh = (const float*)d_in[10];
  const float* W1 = (const float*)d_in[11];
  const float* b1 = (const float*)d_in[12];
  const float* W2 = (const float*)d_in[13];
  const float* b2 = (const float*)d_in[14];

  char* ws = (char*)d_ws;
  size_t off = 0;
  auto take = [&](size_t bytes) {
    char* p = ws + off;
    off += (bytes + 255) & ~(size_t)255;
    return p;
  };
  unsigned short* ln16 = (unsigned short*)take(134217728);  // LN(x) bf16 row-major
  float* Wqk = (float*)take(65536);
  float* Wihv = (float*)take(196608);
  unsigned short* wqk_b = (unsigned short*)take(32768);
  unsigned short* wihv_b = (unsigned short*)take(98304);
  unsigned short* whh_b = (unsigned short*)take(98304);
  unsigned short* w1_b = (unsigned short*)take(65536);
  unsigned short* w2_b = (unsigned short*)take(65536);
  float* slots = (float*)take(524288);
  float* slots_n = (float*)take(524288);
  unsigned short* q2_b = (unsigned short*)take(262144);
  float* upd_part = (float*)take(8388608);    // raw partials (B,16,8,128) fp32
  float* sattn_part = (float*)take(65536);

  k_fold<<<256, 256, 0, stream>>>(Wq, Wk, Wih, Wv, Wqk, Wihv);
  k_pack<<<1216, 256, 0, stream>>>(noise, mu, lsig, Wqk, Wihv, Whh, W1, W2,
                                   slots, wqk_b, wihv_b, whh_b, w1_b, w2_b);
  k_ln<<<65536, 256, 0, stream>>>(x, ln16);
  k_slot_pre<<<64, 64, 0, stream>>>(slots, wqk_b, slots_n, q2_b);
  for (int it = 0; it < 3; it++) {
    k_attn<<<2048, 256, 0, stream>>>(ln16, q2_b, upd_part, sattn_part);
    k_slot_post<<<64, 256, 0, stream>>>(upd_part, sattn_part, slots_n, wihv_b, whh_b,
                                        b_ih, b_hh, w1_b, b1, w2_b, b2, wqk_b,
                                        q2_b, (float*)d_out, (it == 2) ? 1 : 0);
  }
}